// Round 1
// baseline (88.074 us; speedup 1.0000x reference)
//
#include <hip/hip_runtime.h>

#define HID 10
#define NT 5
#define NS 10

__device__ __forceinline__ float sigf(float x) {
    return 1.0f / (1.0f + __expf(-x));
}
__device__ __forceinline__ float tanh_fast(float x) {
    return 2.0f / (1.0f + __expf(-2.0f * x)) - 1.0f;
}

// go1/go2 masks are jnp bool arrays; harness marshaling for bool is not
// documented (int32? float32? raw bytes?). Decode defensively:
//   1) int32 values in {0,1}
//   2) f32 values in {0.0f,1.0f} (bit patterns 0 / 0x3F800000)
//   3) raw 1-byte bools
__device__ __forceinline__ unsigned decode_mask(const void* p) {
    const unsigned* pu = (const unsigned*)p;
    const unsigned char* pb = (const unsigned char*)p;
    unsigned mi = 0, mf = 0, mb = 0;
    bool oki = true, okf = true;
#pragma unroll
    for (int i = 0; i < NS; ++i) {
        unsigned v = pu[i];
        if (v == 1u) mi |= (1u << i);
        else if (v != 0u) oki = false;
        if (v == 0x3F800000u) mf |= (1u << i);
        else if (v != 0u) okf = false;
        if (pb[i]) mb |= (1u << i);
    }
    return oki ? mi : (okf ? mf : mb);
}

__global__ __launch_bounds__(64, 1) void rnnae_kernel(
    const float* __restrict__ omega, const float* __restrict__ noise,
    const void* __restrict__ go1, const void* __restrict__ go2,
    const float* __restrict__ W_ih, const float* __restrict__ W_hh,
    const float* __restrict__ b_ih, const float* __restrict__ b_hh,
    const float* __restrict__ w1, const float* __restrict__ b1,
    const float* __restrict__ w2, const float* __restrict__ b2,
    const float* __restrict__ w3, const float* __restrict__ b3,
    float* __restrict__ out)
{
    const int lane = (int)threadIdx.x;
    float err = 0.0f;

    if (lane < NT * HID) {
        const int t = lane / HID;       // task
        const int u = lane - t * HID;   // hidden unit
        const int grp = t * HID;        // first lane of this task's group

        const unsigned m1 = decode_mask(go1);
        const unsigned m2 = decode_mask(go2);

        const float om = omega[t];
        const bool is_g1 = (fabsf(om - 0.4f) < 1e-4f) || (fabsf(om - 0.8f) < 1e-4f);
        const float scale = is_g1 ? 0.2f : 0.4f;
        const unsigned msk = is_g1 ? m1 : m2;
        const float base = (om - 0.6f) / scale;

        float ah[NS];
#pragma unroll
        for (int st = 0; st < NS; ++st)
            ah[st] = (((msk >> st) & 1u) ? base : 0.0f) + noise[t * NS + st];

        // ---- preload per-lane weights into registers ----
        // LSTM gate rows for this unit (gate order i,f,g,o)
        float wih0[4], wih1[4], whh[4][HID], bg[4];
#pragma unroll
        for (int g = 0; g < 4; ++g) {
            const int r = g * HID + u;
            wih0[g] = W_ih[r * 2 + 0];
            wih1[g] = W_ih[r * 2 + 1];
            bg[g]   = b_ih[r] + b_hh[r];
#pragma unroll
            for (int j = 0; j < HID; ++j) whh[g][j] = W_hh[r * HID + j];
        }
        // MLP rows u and u+HID
        float w1a[HID], w1b[HID];
#pragma unroll
        for (int j = 0; j < HID; ++j) {
            w1a[j] = w1[u * HID + j];
            w1b[j] = w1[(u + HID) * HID + j];
        }
        const float b1a = b1[u], b1b = b1[u + HID];
        float w2a[2 * HID], w2b[2 * HID];
#pragma unroll
        for (int k = 0; k < 2 * HID; ++k) {
            w2a[k] = w2[u * 2 * HID + k];
            w2b[k] = w2[(u + HID) * 2 * HID + k];
        }
        const float b2a = b2[u], b2b = b2[u + HID];
        float w3v[2 * HID];
#pragma unroll
        for (int k = 0; k < 2 * HID; ++k) w3v[k] = w3[k];
        const float b3v = b3[0];

        // ---- rollout ----
        float s = 0.0f, h = 0.0f, c = 0.0f;
#pragma unroll
        for (int st = 0; st < NS; ++st) {
            // broadcast previous h across the task group
            float hj[HID];
#pragma unroll
            for (int j = 0; j < HID; ++j) hj[j] = __shfl(h, grp + j);

            float acc[4];
#pragma unroll
            for (int g = 0; g < 4; ++g) {
                float a = bg[g] + wih0[g] * s + wih1[g] * ah[st];
#pragma unroll
                for (int j = 0; j < HID; ++j) a += whh[g][j] * hj[j];
                acc[g] = a;
            }
            const float ig = sigf(acc[0]);
            const float fg = sigf(acc[1]);
            const float gg = tanh_fast(acc[2]);
            const float og = sigf(acc[3]);
            c = fg * c + ig * gg;
            h = og * tanh_fast(c);

            // broadcast new h
            float hn[HID];
#pragma unroll
            for (int j = 0; j < HID; ++j) hn[j] = __shfl(h, grp + j);

            float x1a = b1a, x1b = b1b;
#pragma unroll
            for (int j = 0; j < HID; ++j) {
                x1a += w1a[j] * hn[j];
                x1b += w1b[j] * hn[j];
            }
            const float h1a = fmaxf(x1a, 0.0f);
            const float h1b = fmaxf(x1b, 0.0f);

            // broadcast h1 (each lane holds h1[u] and h1[u+HID])
            float h1v[2 * HID];
#pragma unroll
            for (int j = 0; j < HID; ++j) {
                h1v[j]       = __shfl(h1a, grp + j);
                h1v[j + HID] = __shfl(h1b, grp + j);
            }
            float x2a = b2a, x2b = b2b;
#pragma unroll
            for (int k = 0; k < 2 * HID; ++k) {
                x2a += w2a[k] * h1v[k];
                x2b += w2b[k] * h1v[k];
            }
            const float h2a = fmaxf(x2a, 0.0f);
            const float h2b = fmaxf(x2b, 0.0f);

            // broadcast h2, every lane computes the full robot action
            float h2v[2 * HID];
#pragma unroll
            for (int j = 0; j < HID; ++j) {
                h2v[j]       = __shfl(h2a, grp + j);
                h2v[j + HID] = __shfl(h2b, grp + j);
            }
            float ar = b3v;
#pragma unroll
            for (int k = 0; k < 2 * HID; ++k) ar += w3v[k] * h2v[k];

            s += ar;
            const float d = s - om;
            err += d * d;   // identical across the task group (uniform ops)
        }
    }

    // cross-task reduction: lanes t*HID hold task-t err (others contribute 0 or dup,
    // we only read the group-leader lanes)
    float tot = 0.0f;
#pragma unroll
    for (int t = 0; t < NT; ++t) tot += __shfl(err, t * HID);
    if (lane == 0) out[0] = tot;
}

extern "C" void kernel_launch(void* const* d_in, const int* in_sizes, int n_in,
                              void* d_out, int out_size, void* d_ws, size_t ws_size,
                              hipStream_t stream) {
    rnnae_kernel<<<1, 64, 0, stream>>>(
        (const float*)d_in[0],   // omega [5]
        (const float*)d_in[1],   // noise [5,10]
        d_in[2],                 // go1_mask [10] (bool, decoded in-kernel)
        d_in[3],                 // go2_mask [10]
        (const float*)d_in[4],   // W_ih [40,2]
        (const float*)d_in[5],   // W_hh [40,10]
        (const float*)d_in[6],   // b_ih [40]
        (const float*)d_in[7],   // b_hh [40]
        (const float*)d_in[8],   // w1 [20,10]
        (const float*)d_in[9],   // b1 [20]
        (const float*)d_in[10],  // w2 [20,20]
        (const float*)d_in[11],  // b2 [20]
        (const float*)d_in[12],  // w3 [1,20]
        (const float*)d_in[13],  // b3 [1]
        (float*)d_out);
}

// Round 2
// 87.300 us; speedup vs baseline: 1.0089x; 1.0089x over previous
//
#include <hip/hip_runtime.h>

#define HID 10
#define NT 5
#define NS 10

__device__ __forceinline__ float sigf(float x) {
    return 1.0f / (1.0f + __expf(-x));
}
__device__ __forceinline__ float tanh_fast(float x) {
    return 2.0f / (1.0f + __expf(-2.0f * x)) - 1.0f;
}

// go1/go2 masks are jnp bool arrays; harness bool marshaling is undocumented.
// Decode defensively: int32 {0,1} -> f32 {0.0,1.0} bit patterns -> raw bytes.
__device__ __forceinline__ unsigned decode_mask(const void* p) {
    const unsigned* pu = (const unsigned*)p;
    const unsigned char* pb = (const unsigned char*)p;
    unsigned mi = 0, mf = 0, mb = 0;
    bool oki = true, okf = true;
#pragma unroll
    for (int i = 0; i < NS; ++i) {
        unsigned v = pu[i];
        if (v == 1u) mi |= (1u << i);
        else if (v != 0u) oki = false;
        if (v == 0x3F800000u) mf |= (1u << i);
        else if (v != 0u) okf = false;
        if (pb[i]) mb |= (1u << i);
    }
    return oki ? mi : (okf ? mf : mb);
}

// One block, one wave. Lane (t,u): task t in [0,5), hidden unit u in [0,10).
// 3 cross-lane phases per step (h broadcast, h1 broadcast, ar gather-sum).
__global__ __launch_bounds__(64, 1) void rnnae_kernel(
    const float* __restrict__ omega, const float* __restrict__ noise,
    const void* __restrict__ go1, const void* __restrict__ go2,
    const float* __restrict__ W_ih, const float* __restrict__ W_hh,
    const float* __restrict__ b_ih, const float* __restrict__ b_hh,
    const float* __restrict__ w1, const float* __restrict__ b1,
    const float* __restrict__ w2, const float* __restrict__ b2,
    const float* __restrict__ w3, const float* __restrict__ b3,
    float* __restrict__ out)
{
    const int lane = (int)threadIdx.x;
    float err = 0.0f;

    if (lane < NT * HID) {
        const int t = lane / HID;
        const int u = lane - t * HID;
        const int grp = t * HID;        // group-leader lane for this task

        const unsigned m1 = decode_mask(go1);
        const unsigned m2 = decode_mask(go2);

        const float om = omega[t];
        const bool is_g1 = (fabsf(om - 0.4f) < 1e-4f) || (fabsf(om - 0.8f) < 1e-4f);
        const float scale = is_g1 ? 0.2f : 0.4f;
        const unsigned msk = is_g1 ? m1 : m2;
        const float base = (om - 0.6f) / scale;

        float ah[NS];
#pragma unroll
        for (int st = 0; st < NS; ++st)
            ah[st] = (((msk >> st) & 1u) ? base : 0.0f) + noise[t * NS + st];

        // ---- per-lane weight preload (registers) ----
        float wih0[4], wih1[4], whh[4][HID], bg[4];
#pragma unroll
        for (int g = 0; g < 4; ++g) {
            const int r = g * HID + u;
            wih0[g] = W_ih[r * 2 + 0];
            wih1[g] = W_ih[r * 2 + 1];
            bg[g]   = b_ih[r] + b_hh[r];
#pragma unroll
            for (int j = 0; j < HID; ++j) whh[g][j] = W_hh[r * HID + j];
        }
        float w1a[HID], w1b[HID];
#pragma unroll
        for (int j = 0; j < HID; ++j) {
            w1a[j] = w1[u * HID + j];
            w1b[j] = w1[(u + HID) * HID + j];
        }
        const float b1a = b1[u], b1b = b1[u + HID];
        float w2a[2 * HID], w2b[2 * HID];
#pragma unroll
        for (int k = 0; k < 2 * HID; ++k) {
            w2a[k] = w2[u * 2 * HID + k];
            w2b[k] = w2[(u + HID) * 2 * HID + k];
        }
        const float b2a = b2[u], b2b = b2[u + HID];
        // only this lane's two w3 entries are needed (partial-product + gather-sum)
        const float w3u  = w3[u];
        const float w3uh = w3[u + HID];
        const float b3v  = b3[0];

        // ---- rollout ----
        float s = 0.0f, c = 0.0f;
        float hj[HID];                  // broadcast h, carried across steps
#pragma unroll
        for (int j = 0; j < HID; ++j) hj[j] = 0.0f;

#pragma unroll
        for (int st = 0; st < NS; ++st) {
            // LSTM gates from carried hj (no broadcast needed here)
            float acc[4];
#pragma unroll
            for (int g = 0; g < 4; ++g) {
                float a = bg[g] + wih0[g] * s + wih1[g] * ah[st];
#pragma unroll
                for (int j = 0; j < HID; ++j) a += whh[g][j] * hj[j];
                acc[g] = a;
            }
            const float ig = sigf(acc[0]);
            const float fg = sigf(acc[1]);
            const float gg = tanh_fast(acc[2]);
            const float og = sigf(acc[3]);
            c = fg * c + ig * gg;
            const float h = og * tanh_fast(c);

            // phase 1: broadcast new h (also feeds next step's gates)
#pragma unroll
            for (int j = 0; j < HID; ++j) hj[j] = __shfl(h, grp + j);

            float x1a = b1a, x1b = b1b;
#pragma unroll
            for (int j = 0; j < HID; ++j) {
                x1a += w1a[j] * hj[j];
                x1b += w1b[j] * hj[j];
            }
            const float h1a = fmaxf(x1a, 0.0f);
            const float h1b = fmaxf(x1b, 0.0f);

            // phase 2: broadcast h1 (lane u holds h1[u], h1[u+HID])
            float h1v[2 * HID];
#pragma unroll
            for (int j = 0; j < HID; ++j) {
                h1v[j]       = __shfl(h1a, grp + j);
                h1v[j + HID] = __shfl(h1b, grp + j);
            }
            float x2a = b2a, x2b = b2b;
#pragma unroll
            for (int k = 0; k < 2 * HID; ++k) {
                x2a += w2a[k] * h1v[k];
                x2b += w2b[k] * h1v[k];
            }
            const float h2a = fmaxf(x2a, 0.0f);
            const float h2b = fmaxf(x2b, 0.0f);

            // phase 3: per-lane partial of the w3 dot, then 10-lane gather-sum
            const float pa = w3u * h2a + w3uh * h2b;
            float ar = b3v;
#pragma unroll
            for (int j = 0; j < HID; ++j) ar += __shfl(pa, grp + j);

            s += ar;
            const float d = s - om;
            err += d * d;               // uniform across the task group
        }
    }

    // cross-task reduction: group-leader lanes hold their task's err
    float tot = 0.0f;
#pragma unroll
    for (int t = 0; t < NT; ++t) tot += __shfl(err, t * HID);
    if (lane == 0) out[0] = tot;
}

extern "C" void kernel_launch(void* const* d_in, const int* in_sizes, int n_in,
                              void* d_out, int out_size, void* d_ws, size_t ws_size,
                              hipStream_t stream) {
    rnnae_kernel<<<1, 64, 0, stream>>>(
        (const float*)d_in[0],   // omega [5]
        (const float*)d_in[1],   // noise [5,10]
        d_in[2],                 // go1_mask [10] (bool, decoded in-kernel)
        d_in[3],                 // go2_mask [10]
        (const float*)d_in[4],   // W_ih [40,2]
        (const float*)d_in[5],   // W_hh [40,10]
        (const float*)d_in[6],   // b_ih [40]
        (const float*)d_in[7],   // b_hh [40]
        (const float*)d_in[8],   // w1 [20,10]
        (const float*)d_in[9],   // b1 [20]
        (const float*)d_in[10],  // w2 [20,20]
        (const float*)d_in[11],  // b2 [20]
        (const float*)d_in[12],  // w3 [1,20]
        (const float*)d_in[13],  // b3 [1]
        (float*)d_out);
}